// Round 18
// baseline (433.146 us; speedup 1.0000x reference)
//
#include <hip/hip_runtime.h>

// EdgeBlock: out = relu(concat(node[snd], node[rcv], edge) @ w1 + b1) @ w2 + b2
// E=800000, N=50000, D=128. fp32 in/out, fp16 MFMA.
// r18: 16x16x32, 512thr (8 waves), LDS = 96KB w1t + 8 x (2x4KB dbuf) = 160KB.
//   S/R node gathers via global_load_lds (ZERO registers, per-lane pre-swizzled
//   global src -> linear LDS dest, m173 pattern). 4 tiles/wave; next tile's S
//   issued post-GEMM2 into the freed R buffer (cross-tile prefetch with no
//   register cost -- the thing that spilled 6x via registers).
//   Counted waits: vmcnt(44) at tile top (stores32+R4+ev8 after S), vmcnt(0)
//   before seg1 (free: compiler already drained via ev use). nt stores (r17:
//   plain stores pollute L2, +34MB refetch, -0.4TB/s).

#define NE 800000
#define DD 128

typedef float f32x4v __attribute__((ext_vector_type(4)));
typedef float f32x4a __attribute__((ext_vector_type(4)));
typedef _Float16 f16x8 __attribute__((ext_vector_type(8)));
typedef _Float16 f16x4 __attribute__((ext_vector_type(4)));

__device__ __forceinline__ f16x4 cvt4(f32x4v v) {
    f16x4 r;
    r[0] = (_Float16)v[0]; r[1] = (_Float16)v[1];
    r[2] = (_Float16)v[2]; r[3] = (_Float16)v[3];
    return r;
}

// w1[384][128] -> w1t swizzled fp16: byte = col*768 + ((k*2) ^ ((col&15)<<4))   (96KB)
// w2[128][128] -> w2f fragment-major fp16: w2f[(ks*128 + col)*8 + j] = w2[ks*8+j][col] (32KB)
__global__ void prep_w(const float* __restrict__ w1, const float* __restrict__ w2,
                       _Float16* __restrict__ w1t, _Float16* __restrict__ w2f) {
    int i = blockIdx.x * 256 + threadIdx.x;   // 65536 total
    if (i < 384 * 128) {
        int col = i / 384;
        int k = i - col * 384;
        float v = w1[(size_t)k * 128 + col];
        int byteoff = col * 768 + ((k * 2) ^ ((col & 15) << 4));
        *(_Float16*)((char*)w1t + byteoff) = (_Float16)v;
    } else {
        int j = i - 384 * 128;
        int ks = j >> 10;
        int col = (j >> 3) & 127;
        int jj = j & 7;
        w2f[j] = (_Float16)w2[(size_t)(ks * 8 + jj) * 128 + col];
    }
}

// node_attr fp32 [50000][128] -> nf16 fp16 [50000][128]
__global__ void prep_node(const float* __restrict__ node_attr, _Float16* __restrict__ nf16) {
    int i = blockIdx.x * 256 + threadIdx.x;   // x8 elems: 3125 blocks
    const float* src = node_attr + (size_t)i * 8;
    f32x4v a = *(const f32x4v*)src;
    f32x4v b = *(const f32x4v*)(src + 4);
    f16x8 r;
    r[0] = (_Float16)a[0]; r[1] = (_Float16)a[1];
    r[2] = (_Float16)a[2]; r[3] = (_Float16)a[3];
    r[4] = (_Float16)b[0]; r[5] = (_Float16)b[1];
    r[6] = (_Float16)b[2]; r[7] = (_Float16)b[3];
    *(f16x8*)(nf16 + (size_t)i * 8) = r;
}

// MFMA over one staged segment: 4 K-steps (K=32) A from BUF, B from w1t in lds.
#define MFMA_SEG(BUF, SEG)                                                                \
    _Pragma("unroll")                                                                     \
    for (int kk = 0; kk < 4; kk++) {                                                      \
        f16x8 a = *(const f16x8*)((BUF) + r15 * 256 + ((kk * 64 + q16) ^ xa));            \
        _Pragma("unroll")                                                                 \
        for (int n = 0; n < 8; n++) {                                                     \
            const int col = n * 16 + r15;                                                 \
            f16x8 b = *(const f16x8*)(lds + col * 768 +                                   \
                       ((((SEG) * 4 + kk) * 64 + q16) ^ xa));                             \
            acc[n] = __builtin_amdgcn_mfma_f32_16x16x32_f16(a, b, acc[n], 0, 0, 0);       \
        }                                                                                 \
    }

__global__ __attribute__((amdgpu_flat_work_group_size(512, 512),
                          amdgpu_waves_per_eu(2, 2)))
void edge_mlp(
    const float* __restrict__ node_attr,   // unused
    const int* __restrict__ eidx,
    const float* __restrict__ edge_attr,
    const _Float16* __restrict__ w1t,   // swizzled, 96KB
    const float* __restrict__ b1,
    const _Float16* __restrict__ w2f,   // fragment-major, 32KB
    const float* __restrict__ b2,
    const _Float16* __restrict__ nf16,  // fp16 node rows, 12.8MB (L3-resident)
    float* __restrict__ out) {
    extern __shared__ char lds[];   // [0,96K): w1t swz   [96K + wid*8K): 2x4KB per wave

    const int tid = threadIdx.x;
    const int wid = tid >> 6;        // 0..7
    const int lane = tid & 63;
    const int r15 = lane & 15;
    const int q16 = (lane >> 4) * 16;
    const int sub = lane >> 5;
    const int c31 = lane & 31;
    const int xa = r15 << 4;

    // ---- per-wave tile bases + indices (before staging, for cover) ----
    const int gb = blockIdx.x * 512 + wid * 64;
    int eb[4]; int sid[4]; int rid[4];
    #pragma unroll
    for (int t = 0; t < 4; t++) {
        int e = gb + t * 16;
        if (e > NE - 16) e = NE - 16;   // tail clamp (idempotent dup writes)
        eb[t] = e;
        sid[t] = eidx[e + r15];
        rid[t] = eidx[NE + e + r15];
    }

    // ---- stage w1t -> LDS ----
    {
        const char* src = (const char*)w1t;
        #pragma unroll
        for (int i = 0; i < 12; i++) {
            int off = (tid + i * 512) * 16;   // 512*12*16B = 96KB
            *(f16x8*)(lds + off) = *(const f16x8*)(src + off);
        }
    }

    float b1v[8], b2v[8];
    #pragma unroll
    for (int n = 0; n < 8; n++) { b1v[n] = b1[n * 16 + r15]; b2v[n] = b2[n * 16 + r15]; }

    __syncthreads();

    char* ab0 = lds + 96 * 1024 + wid * 8192;
    char* ab1 = ab0 + 4096;

    // ---- async gather: 16 fp16 rows -> linear LDS, src pre-swizzled (m173) ----
    // instr j covers rows 4j..4j+3; lane l -> row 4j+(l>>4), 16B chunk l&15.
    // LDS linear pos row*256+q must hold src byte q ^ ((row&15)<<4).
#define GATHER_SEG(IDX, BUF)                                                              \
    {                                                                                     \
        _Pragma("unroll")                                                                 \
        for (int j = 0; j < 4; j++) {                                                     \
            const int row = 4 * j + (lane >> 4);                                          \
            const int rr = __shfl((IDX), row);                                            \
            const int q = (lane & 15) * 16;                                               \
            const char* srcp = (const char*)(nf16 + (size_t)rr * DD)                      \
                               + (q ^ ((row & 15) << 4));                                 \
            __builtin_amdgcn_global_load_lds(                                             \
                (const __attribute__((address_space(1))) void*)srcp,                      \
                (__attribute__((address_space(3))) void*)((BUF) + j * 1024),              \
                16, 0, 0);                                                                \
        }                                                                                 \
    }

    // prologue: S_0 -> ab0, drain once
    GATHER_SEG(sid[0], ab0)
    asm volatile("s_waitcnt vmcnt(0)" ::: "memory");

#define TILE_BODY(T, BS, BR, DO_NEXT, NBUF)                                               \
    {                                                                                     \
        const int ebase = eb[T];                                                          \
        GATHER_SEG(rid[T], BR)                       /* R -> BR (+4) */                   \
        f32x4v ev[8];                                                                     \
        _Pragma("unroll")                                                                 \
        for (int i = 0; i < 8; i++) {                 /* +8 */                            \
            const int row = 2 * i + sub;                                                  \
            ev[i] = __builtin_nontemporal_load(                                           \
                (const f32x4v*)(edge_attr + (size_t)(ebase + row) * DD + c31 * 4));       \
        }                                                                                 \
        /* S ready: 44 = stores(32)+R(4)+ev(8) issued after S (t=0: already drained) */   \
        asm volatile("s_waitcnt vmcnt(44)" ::: "memory");                                 \
        __builtin_amdgcn_sched_barrier(0);                                                \
        f32x4a acc[8] = {};                                                               \
        __builtin_amdgcn_wave_barrier();                                                  \
        MFMA_SEG(BS, 0)                                                                   \
        /* E -> BS (compiler drains ev; in-order => R landed too) */                      \
        _Pragma("unroll")                                                                 \
        for (int i = 0; i < 8; i++) {                                                     \
            const int row = 2 * i + sub;                                                  \
            *(f16x4*)((BS) + row * 256 + ((c31 * 8) ^ ((row & 15) << 4))) = cvt4(ev[i]);  \
        }                                                                                 \
        asm volatile("s_waitcnt vmcnt(0)" ::: "memory");  /* belt+braces: R in LDS */     \
        __builtin_amdgcn_sched_barrier(0);                                                \
        __builtin_amdgcn_wave_barrier();                                                  \
        MFMA_SEG(BR, 1)                                                                   \
        __builtin_amdgcn_wave_barrier();                                                  \
        MFMA_SEG(BS, 2)                                                                   \
        /* bias + relu, h -> BS */                                                        \
        _Pragma("unroll")                                                                 \
        for (int n = 0; n < 8; n++) {                                                     \
            const int col = n * 16 + r15;                                                 \
            _Pragma("unroll")                                                             \
            for (int reg = 0; reg < 4; reg++) {                                           \
                const int row = (lane >> 4) * 4 + reg;                                    \
                float v = fmaxf(acc[n][reg] + b1v[n], 0.0f);                              \
                *(_Float16*)((BS) + row * 256 + ((col * 2) ^ ((row & 15) << 4))) =        \
                    (_Float16)v;                                                          \
            }                                                                             \
        }                                                                                 \
        __builtin_amdgcn_wave_barrier();                                                  \
        /* GEMM2 */                                                                       \
        f32x4a acc2[8] = {};                                                              \
        f16x8 b2fa[2][8];                                                                 \
        _Pragma("unroll")                                                                 \
        for (int kk = 0; kk < 2; kk++)                                                    \
            _Pragma("unroll")                                                             \
            for (int n = 0; n < 8; n++) {                                                 \
                const int ks = kk * 4 + (lane >> 4);                                      \
                b2fa[kk][n] = *(const f16x8*)(w2f + ((size_t)(ks * 128 + n * 16 + r15)) * 8); \
            }                                                                             \
        _Pragma("unroll")                                                                 \
        for (int kk = 0; kk < 2; kk++) {                                                  \
            f16x8 a = *(const f16x8*)((BS) + r15 * 256 + ((kk * 64 + q16) ^ xa));         \
            _Pragma("unroll")                                                             \
            for (int n = 0; n < 8; n++)                                                   \
                acc2[n] = __builtin_amdgcn_mfma_f32_16x16x32_f16(a, b2fa[kk][n], acc2[n], 0, 0, 0); \
        }                                                                                 \
        f16x8 b2fb[2][8];                                                                 \
        _Pragma("unroll")                                                                 \
        for (int kk = 0; kk < 2; kk++)                                                    \
            _Pragma("unroll")                                                             \
            for (int n = 0; n < 8; n++) {                                                 \
                const int ks = (kk + 2) * 4 + (lane >> 4);                                \
                b2fb[kk][n] = *(const f16x8*)(w2f + ((size_t)(ks * 128 + n * 16 + r15)) * 8); \
            }                                                                             \
        _Pragma("unroll")                                                                 \
        for (int kk = 2; kk < 4; kk++) {                                                  \
            f16x8 a = *(const f16x8*)((BS) + r15 * 256 + ((kk * 64 + q16) ^ xa));         \
            _Pragma("unroll")                                                             \
            for (int n = 0; n < 8; n++)                                                   \
                acc2[n] = __builtin_amdgcn_mfma_f32_16x16x32_f16(a, b2fb[kk - 2][n], acc2[n], 0, 0, 0); \
        }                                                                                 \
        /* cross-tile: S_{T+1} -> NBUF (zero registers) */                                \
        if (DO_NEXT) { GATHER_SEG(sid[(T) + 1], NBUF) }                                   \
        asm volatile("" ::: "memory");                                                    \
        /* nt stores (keep L2 clean for gathers; r17 lesson) */                           \
        _Pragma("unroll")                                                                 \
        for (int n = 0; n < 8; n++) {                                                     \
            _Pragma("unroll")                                                             \
            for (int reg = 0; reg < 4; reg++) {                                           \
                const int row = (lane >> 4) * 4 + reg;                                    \
                __builtin_nontemporal_store(acc2[n][reg] + b2v[n],                        \
                    out + (size_t)(ebase + row) * DD + n * 16 + r15);                     \
            }                                                                             \
        }                                                                                 \
        asm volatile("" ::: "memory");                                                    \
    }

    TILE_BODY(0, ab0, ab1, 1, ab1)
    TILE_BODY(1, ab1, ab0, 1, ab0)
    TILE_BODY(2, ab0, ab1, 1, ab1)
    TILE_BODY(3, ab1, ab0, 0, ab0)
}

extern "C" void kernel_launch(void* const* d_in, const int* in_sizes, int n_in,
                              void* d_out, int out_size, void* d_ws, size_t ws_size,
                              hipStream_t stream) {
    const float* node_attr = (const float*)d_in[0];
    const int* eidx = (const int*)d_in[1];
    const float* edge_attr = (const float*)d_in[2];
    const float* w1 = (const float*)d_in[3];
    const float* b1 = (const float*)d_in[4];
    const float* w2 = (const float*)d_in[5];
    const float* b2 = (const float*)d_in[6];
    float* out = (float*)d_out;

    _Float16* w1t = (_Float16*)d_ws;            // 96KB swizzled
    _Float16* w2f = w1t + 384 * 128;            // 32KB fragment-major
    _Float16* nf16 = w2f + 128 * 128;           // 12.8MB fp16 node rows

    hipFuncSetAttribute((const void*)edge_mlp,
                        hipFuncAttributeMaxDynamicSharedMemorySize, 160 * 1024);

    prep_w<<<256, 256, 0, stream>>>(w1, w2, w1t, w2f);
    prep_node<<<3125, 256, 0, stream>>>(node_attr, nf16);
    // 1563 blocks x 8 waves x 4 tiles x 16 edges = 800,256 (tail clamped)
    edge_mlp<<<1563, 512, 160 * 1024, stream>>>(node_attr, eidx, edge_attr,
                                                w1t, b1, w2f, b2, nf16, out);
}

// Round 19
// 231.111 us; speedup vs baseline: 1.8742x; 1.8742x over previous
//
#include <hip/hip_runtime.h>

// EdgeBlock: out = relu(concat(node[snd], node[rcv], edge) @ w1 + b1) @ w2 + b2
// E=800000, N=50000, D=128. fp32 in/out, fp16 MFMA.
// r19 = r11 CHAMPION resubmitted verbatim (232us):
//   - node_attr pre-cast fp16 (gather bytes halved, L3-resident)
//   - w1^T swizzled in LDS (96KB), per-wave 8KB A/h buffer, 0 bank conflicts
//   - 2-row-per-instruction gathers (minimal transactions)
//   - S->R->E stage order (r13: E-first worse), rv/ev under MFMA cover
//   - nt stores (full 128B lines at 32x32 geometry; r17: plain stores pollute L2)
//   - NO cross-tile prefetch (7/7 attempts spill: r7,r10,r12,r14,r16,r18)

#define NE 800000
#define ND 50000
#define DD 128

typedef float f32x4v __attribute__((ext_vector_type(4)));
typedef float f32x16 __attribute__((ext_vector_type(16)));
typedef _Float16 f16x8 __attribute__((ext_vector_type(8)));
typedef _Float16 f16x4 __attribute__((ext_vector_type(4)));

__device__ __forceinline__ f16x4 cvt4(f32x4v v) {
    f16x4 r;
    r[0] = (_Float16)v[0]; r[1] = (_Float16)v[1];
    r[2] = (_Float16)v[2]; r[3] = (_Float16)v[3];
    return r;
}

// w1[384][128] -> w1t swizzled fp16: byte = col*768 + ((k*2) ^ ((col&15)<<4))   (96KB)
// w2[128][128] -> w2f fragment-major fp16: w2f[(kk2*128 + col)*8 + j] = w2[kk2*8+j][col] (32KB)
__global__ void prep_w(const float* __restrict__ w1, const float* __restrict__ w2,
                       _Float16* __restrict__ w1t, _Float16* __restrict__ w2f) {
    int i = blockIdx.x * 256 + threadIdx.x;   // 65536 total
    if (i < 384 * 128) {
        int col = i / 384;
        int k = i - col * 384;
        float v = w1[(size_t)k * 128 + col];
        int byteoff = col * 768 + ((k * 2) ^ ((col & 15) << 4));
        *(_Float16*)((char*)w1t + byteoff) = (_Float16)v;
    } else {
        int j = i - 384 * 128;                // 0..16383
        int kk2 = j >> 10;                    // 0..15
        int col = (j >> 3) & 127;
        int jj = j & 7;
        w2f[j] = (_Float16)w2[(size_t)(kk2 * 8 + jj) * 128 + col];
    }
}

// node_attr fp32 [50000][128] -> nf16 fp16 [50000][128]
__global__ void prep_node(const float* __restrict__ node_attr, _Float16* __restrict__ nf16) {
    int i = blockIdx.x * 256 + threadIdx.x;   // x8 elems: 3125 blocks
    const float* src = node_attr + (size_t)i * 8;
    f32x4v a = *(const f32x4v*)src;
    f32x4v b = *(const f32x4v*)(src + 4);
    f16x8 r;
    r[0] = (_Float16)a[0]; r[1] = (_Float16)a[1];
    r[2] = (_Float16)a[2]; r[3] = (_Float16)a[3];
    r[4] = (_Float16)b[0]; r[5] = (_Float16)b[1];
    r[6] = (_Float16)b[2]; r[7] = (_Float16)b[3];
    *(f16x8*)(nf16 + (size_t)i * 8) = r;
}

__global__ __attribute__((amdgpu_flat_work_group_size(512, 512),
                          amdgpu_waves_per_eu(2, 2)))
void edge_mlp(
    const float* __restrict__ node_attr,   // unused
    const int* __restrict__ eidx,
    const float* __restrict__ edge_attr,
    const _Float16* __restrict__ w1t,   // swizzled, 96KB
    const float* __restrict__ b1,
    const _Float16* __restrict__ w2f,   // fragment-major, 32KB
    const float* __restrict__ b2,
    const _Float16* __restrict__ nf16,  // fp16 node rows, 12.8MB (L3-resident)
    float* __restrict__ out) {
    extern __shared__ char lds[];   // [0,96K): w1t swz   [96K + wid*8K): A/h per wave

    const int tid = threadIdx.x;
    const int wid = tid >> 6;
    const int lane = tid & 63;
    const int r31 = lane & 31;
    const int g2 = lane >> 5;
    const int sub = g2;           // row selector within gathered pair
    const int c4 = r31;           // 8B-chunk index within row

    // ---- stage w1t -> LDS (linear copy of pre-swizzled data) ----
    {
        const char* src = (const char*)w1t;
        #pragma unroll
        for (int i = 0; i < 12; i++) {
            int off = (tid + i * 512) * 16;   // 512*12*16B = 96KB
            *(f16x8*)(lds + off) = *(const f16x8*)(src + off);
        }
    }

    float b1v[4], b2v[4];
    #pragma unroll
    for (int n = 0; n < 4; n++) { b1v[n] = b1[n * 32 + r31]; b2v[n] = b2[n * 32 + r31]; }

    __syncthreads();

    char* ab = lds + 96 * 1024 + wid * 8192;
    const int ebase = blockIdx.x * 256 + wid * 32;
    const int xa = (r31 & 15) << 4;   // A-read swizzle

    const int sidx = eidx[ebase + r31];
    const int ridx = eidx[NE + ebase + r31];

    // ---- gather sender rows: fp16, 2 rows/instr (2x256B), 8B/lane ----
    f16x4 sv[16];
    #pragma unroll
    for (int i = 0; i < 16; i++) {
        int r = __shfl(sidx, 2 * i + sub);
        sv[i] = *(const f16x4*)(nf16 + (size_t)r * DD + c4 * 4);
    }
    // write seg S to LDS (direct fp16, swizzled)
    #pragma unroll
    for (int i = 0; i < 16; i++) {
        const int row = 2 * i + sub;
        *(f16x4*)(ab + row * 256 + ((c4 * 8) ^ ((row & 15) << 4))) = sv[i];
    }

    // issue receiver gathers (fly during seg-S MFMAs)
    f16x4 rv[16];
    #pragma unroll
    for (int i = 0; i < 16; i++) {
        int r = __shfl(ridx, 2 * i + sub);
        rv[i] = *(const f16x4*)(nf16 + (size_t)r * DD + c4 * 4);
    }

    f32x16 acc[4] = {};
    __builtin_amdgcn_wave_barrier();

    // ---- consume seg 0 (sender) ----
    #pragma unroll
    for (int kk8 = 0; kk8 < 8; kk8++) {
        f16x8 a = *(const f16x8*)(ab + r31 * 256 + ((kk8 * 32 + g2 * 16) ^ xa));
        #pragma unroll
        for (int n = 0; n < 4; n++) {
            const int col = n * 32 + r31;
            f16x8 b = *(const f16x8*)(lds + col * 768 + (((0 * 8 + kk8) * 32 + g2 * 16) ^ ((col & 15) << 4)));
            acc[n] = __builtin_amdgcn_mfma_f32_32x32x16_f16(a, b, acc[n], 0, 0, 0);
        }
    }

    // write seg R, issue edge loads
    #pragma unroll
    for (int i = 0; i < 16; i++) {
        const int row = 2 * i + sub;
        *(f16x4*)(ab + row * 256 + ((c4 * 8) ^ ((row & 15) << 4))) = rv[i];
    }
    f32x4v ev[16];
    #pragma unroll
    for (int i = 0; i < 16; i++) {
        const int row = 2 * i + sub;
        ev[i] = __builtin_nontemporal_load(
            (const f32x4v*)(edge_attr + (size_t)(ebase + row) * DD + c4 * 4));
    }
    __builtin_amdgcn_wave_barrier();

    // ---- consume seg 1 (receiver) ----
    #pragma unroll
    for (int kk8 = 0; kk8 < 8; kk8++) {
        f16x8 a = *(const f16x8*)(ab + r31 * 256 + ((kk8 * 32 + g2 * 16) ^ xa));
        #pragma unroll
        for (int n = 0; n < 4; n++) {
            const int col = n * 32 + r31;
            f16x8 b = *(const f16x8*)(lds + col * 768 + (((1 * 8 + kk8) * 32 + g2 * 16) ^ ((col & 15) << 4)));
            acc[n] = __builtin_amdgcn_mfma_f32_32x32x16_f16(a, b, acc[n], 0, 0, 0);
        }
    }

    // write seg E (cvt fp32->fp16); prefetch GEMM2 B half-0
    #pragma unroll
    for (int i = 0; i < 16; i++) {
        const int row = 2 * i + sub;
        *(f16x4*)(ab + row * 256 + ((c4 * 8) ^ ((row & 15) << 4))) = cvt4(ev[i]);
    }
    f16x8 b2fa[4][4];
    #pragma unroll
    for (int kk = 0; kk < 4; kk++)
        #pragma unroll
        for (int n = 0; n < 4; n++)
            b2fa[kk][n] = *(const f16x8*)(w2f + ((size_t)((kk * 2 + g2) * 128 + n * 32 + r31)) * 8);
    __builtin_amdgcn_wave_barrier();

    // ---- consume seg 2 (edge) ----
    #pragma unroll
    for (int kk8 = 0; kk8 < 8; kk8++) {
        f16x8 a = *(const f16x8*)(ab + r31 * 256 + ((kk8 * 32 + g2 * 16) ^ xa));
        #pragma unroll
        for (int n = 0; n < 4; n++) {
            const int col = n * 32 + r31;
            f16x8 b = *(const f16x8*)(lds + col * 768 + (((2 * 8 + kk8) * 32 + g2 * 16) ^ ((col & 15) << 4)));
            acc[n] = __builtin_amdgcn_mfma_f32_32x32x16_f16(a, b, acc[n], 0, 0, 0);
        }
    }

    // ---- bias + relu, h -> same LDS buffer (seg data dead) ----
    #pragma unroll
    for (int n = 0; n < 4; n++) {
        const int col = n * 32 + r31;
        #pragma unroll
        for (int reg = 0; reg < 16; reg++) {
            const int row = (reg & 3) + 8 * (reg >> 2) + 4 * g2;
            float v = fmaxf(acc[n][reg] + b1v[n], 0.0f);
            *(_Float16*)(ab + row * 256 + ((col * 2) ^ ((row & 15) << 4))) = (_Float16)v;
        }
    }
    __builtin_amdgcn_wave_barrier();

    // ---------------- GEMM2: [32x128] @ [128x128] ----------------
    f32x16 acc2[4] = {};
    #pragma unroll
    for (int kk = 0; kk < 4; kk++) {
        f16x8 a = *(const f16x8*)(ab + r31 * 256 + ((kk * 32 + g2 * 16) ^ xa));
        #pragma unroll
        for (int n = 0; n < 4; n++)
            acc2[n] = __builtin_amdgcn_mfma_f32_32x32x16_f16(a, b2fa[kk][n], acc2[n], 0, 0, 0);
    }
    f16x8 b2fb[4][4];
    #pragma unroll
    for (int kk = 0; kk < 4; kk++)
        #pragma unroll
        for (int n = 0; n < 4; n++)
            b2fb[kk][n] = *(const f16x8*)(w2f + ((size_t)(((kk + 4) * 2 + g2) * 128 + n * 32 + r31)) * 8);
    #pragma unroll
    for (int kk = 4; kk < 8; kk++) {
        f16x8 a = *(const f16x8*)(ab + r31 * 256 + ((kk * 32 + g2 * 16) ^ xa));
        #pragma unroll
        for (int n = 0; n < 4; n++)
            acc2[n] = __builtin_amdgcn_mfma_f32_32x32x16_f16(a, b2fb[kk - 4][n], acc2[n], 0, 0, 0);
    }

    // ---- bias + store fp32 (coalesced 128B lines, nontemporal) ----
    #pragma unroll
    for (int n = 0; n < 4; n++) {
        #pragma unroll
        for (int reg = 0; reg < 16; reg++) {
            const int row = (reg & 3) + 8 * (reg >> 2) + 4 * g2;
            __builtin_nontemporal_store(acc2[n][reg] + b2v[n],
                out + (size_t)(ebase + row) * DD + n * 32 + r31);
        }
    }
}

extern "C" void kernel_launch(void* const* d_in, const int* in_sizes, int n_in,
                              void* d_out, int out_size, void* d_ws, size_t ws_size,
                              hipStream_t stream) {
    const float* node_attr = (const float*)d_in[0];
    const int* eidx = (const int*)d_in[1];
    const float* edge_attr = (const float*)d_in[2];
    const float* w1 = (const float*)d_in[3];
    const float* b1 = (const float*)d_in[4];
    const float* w2 = (const float*)d_in[5];
    const float* b2 = (const float*)d_in[6];
    float* out = (float*)d_out;

    _Float16* w1t = (_Float16*)d_ws;            // 96KB swizzled
    _Float16* w2f = w1t + 384 * 128;            // 32KB fragment-major
    _Float16* nf16 = w2f + 128 * 128;           // 12.8MB fp16 node rows

    hipFuncSetAttribute((const void*)edge_mlp,
                        hipFuncAttributeMaxDynamicSharedMemorySize, 160 * 1024);

    prep_w<<<256, 256, 0, stream>>>(w1, w2, w1t, w2f);
    prep_node<<<3125, 256, 0, stream>>>(node_attr, nf16);
    edge_mlp<<<3125, 512, 160 * 1024, stream>>>(node_attr, eidx, edge_attr,
                                                w1t, b1, w2f, b2, nf16, out);
}